// Round 2
// baseline (3918.314 us; speedup 1.0000x reference)
//
#include <hip/hip_runtime.h>

#define B_SZ 32
#define N_TOK 3136
#define C_DIM 512
#define H_IMG 56
#define NUM_HEADS 8
#define HEAD_DIM 64
#define AGENT_NUM 49
#define SCALE 0.125f
#define M_ROWS (B_SZ * N_TOK)        // 100352
#define N_SPLIT 7                    // agent-attn n-splits (448 tokens each)

static __device__ __forceinline__ unsigned short f2bf(float f) {
    unsigned int u = __float_as_uint(f);
    unsigned int r = (u + 0x7fffu + ((u >> 16) & 1u)) >> 16;   // RNE
    return (unsigned short)r;
}
static __device__ __forceinline__ float bf2f(unsigned short u) {
    return __uint_as_float(((unsigned int)u) << 16);
}

// ---------------------------------------------------------------------------
// QKV GEMM: [M,1536] = x[M,512] @ qkv_w[1536,512]^T
// q (cols 0:512) -> fp32 into d_out;  k,v (cols 512:1024, 1024:1536) -> bf16 ws
// BM=BN=128, BK=16, 256 threads, 8x8 microtile.
// ---------------------------------------------------------------------------
__global__ __launch_bounds__(256) void sgemm_qkv(
    const float* __restrict__ A, const float* __restrict__ W,
    float* __restrict__ qO, unsigned short* __restrict__ kO,
    unsigned short* __restrict__ vO)
{
    __shared__ float As[16][132];
    __shared__ float Bs[16][132];
    int m0 = blockIdx.x * 128;
    int n0 = blockIdx.y * 128;
    int tid = threadIdx.x;
    int tx = tid & 15, ty = tid >> 4;

    float acc[8][8];
#pragma unroll
    for (int i = 0; i < 8; i++)
#pragma unroll
        for (int j = 0; j < 8; j++) acc[i][j] = 0.f;

    for (int k0 = 0; k0 < 512; k0 += 16) {
#pragma unroll
        for (int it = 0; it < 2; it++) {
            int f = it * 256 + tid;
            int m = f >> 2;
            int k4 = (f & 3) << 2;
            float4 a4 = *(const float4*)(A + (long)(m0 + m) * 512 + k0 + k4);
            As[k4 + 0][m] = a4.x; As[k4 + 1][m] = a4.y;
            As[k4 + 2][m] = a4.z; As[k4 + 3][m] = a4.w;
            float4 b4 = *(const float4*)(W + (long)(n0 + m) * 512 + k0 + k4);
            Bs[k4 + 0][m] = b4.x; Bs[k4 + 1][m] = b4.y;
            Bs[k4 + 2][m] = b4.z; Bs[k4 + 3][m] = b4.w;
        }
        __syncthreads();
#pragma unroll
        for (int k = 0; k < 16; k++) {
            float ar[8], br[8];
#pragma unroll
            for (int i = 0; i < 8; i++) ar[i] = As[k][ty * 8 + i];
#pragma unroll
            for (int j = 0; j < 8; j++) br[j] = Bs[k][tx * 8 + j];
#pragma unroll
            for (int i = 0; i < 8; i++)
#pragma unroll
                for (int j = 0; j < 8; j++) acc[i][j] += ar[i] * br[j];
        }
        __syncthreads();
    }

    int seg = n0 >> 9;                 // 0=q, 1=k, 2=v (BN=128 divides 512)
#pragma unroll
    for (int i = 0; i < 8; i++) {
        long m = m0 + ty * 8 + i;
#pragma unroll
        for (int j4 = 0; j4 < 2; j4++) {
            int nn = n0 + tx * 8 + j4 * 4;
            int nloc = nn - (seg << 9);
            float vx = acc[i][j4 * 4 + 0], vy = acc[i][j4 * 4 + 1];
            float vz = acc[i][j4 * 4 + 2], vw = acc[i][j4 * 4 + 3];
            if (seg == 0) {
                float4 o = make_float4(vx, vy, vz, vw);
                *(float4*)(qO + m * 512 + nloc) = o;
            } else {
                ushort4 o;
                o.x = f2bf(vx); o.y = f2bf(vy); o.z = f2bf(vz); o.w = f2bf(vw);
                unsigned short* dst = (seg == 1 ? kO : vO) + m * 512 + nloc;
                *(ushort4*)dst = o;
            }
        }
    }
}

// ---------------------------------------------------------------------------
// Proj GEMM: d_out[M,512] = A_bf16[M,512] @ proj_w[512,512]^T + proj_b
// ---------------------------------------------------------------------------
__global__ __launch_bounds__(256) void sgemm_proj(
    const unsigned short* __restrict__ A, const float* __restrict__ W,
    const float* __restrict__ bias, float* __restrict__ C)
{
    __shared__ float As[16][132];
    __shared__ float Bs[16][132];
    int m0 = blockIdx.x * 128;
    int n0 = blockIdx.y * 128;
    int tid = threadIdx.x;
    int tx = tid & 15, ty = tid >> 4;

    float acc[8][8];
#pragma unroll
    for (int i = 0; i < 8; i++)
#pragma unroll
        for (int j = 0; j < 8; j++) acc[i][j] = 0.f;

    for (int k0 = 0; k0 < 512; k0 += 16) {
#pragma unroll
        for (int it = 0; it < 2; it++) {
            int f = it * 256 + tid;
            int m = f >> 2;
            int k4 = (f & 3) << 2;
            ushort4 a4 = *(const ushort4*)(A + (long)(m0 + m) * 512 + k0 + k4);
            As[k4 + 0][m] = bf2f(a4.x); As[k4 + 1][m] = bf2f(a4.y);
            As[k4 + 2][m] = bf2f(a4.z); As[k4 + 3][m] = bf2f(a4.w);
            float4 b4 = *(const float4*)(W + (long)(n0 + m) * 512 + k0 + k4);
            Bs[k4 + 0][m] = b4.x; Bs[k4 + 1][m] = b4.y;
            Bs[k4 + 2][m] = b4.z; Bs[k4 + 3][m] = b4.w;
        }
        __syncthreads();
#pragma unroll
        for (int k = 0; k < 16; k++) {
            float ar[8], br[8];
#pragma unroll
            for (int i = 0; i < 8; i++) ar[i] = As[k][ty * 8 + i];
#pragma unroll
            for (int j = 0; j < 8; j++) br[j] = Bs[k][tx * 8 + j];
#pragma unroll
            for (int i = 0; i < 8; i++)
#pragma unroll
                for (int j = 0; j < 8; j++) acc[i][j] += ar[i] * br[j];
        }
        __syncthreads();
    }

#pragma unroll
    for (int i = 0; i < 8; i++) {
        long m = m0 + ty * 8 + i;
#pragma unroll
        for (int j4 = 0; j4 < 2; j4++) {
            int nn = n0 + tx * 8 + j4 * 4;
            float4 o;
            o.x = acc[i][j4 * 4 + 0] + bias[nn + 0];
            o.y = acc[i][j4 * 4 + 1] + bias[nn + 1];
            o.z = acc[i][j4 * 4 + 2] + bias[nn + 2];
            o.w = acc[i][j4 * 4 + 3] + bias[nn + 3];
            *(float4*)(C + m * 512 + nn) = o;
        }
    }
}

// ---------------------------------------------------------------------------
// agent[b,a,c] = mean over 8x8 spatial block of q (q fp32, stride 512)
// ---------------------------------------------------------------------------
__global__ __launch_bounds__(256) void pool_q(
    const float* __restrict__ q, float* __restrict__ agent)
{
    int blk = blockIdx.x;
    int half = blk & 1;
    int a = (blk >> 1) % AGENT_NUM;
    int b = blk / (2 * AGENT_NUM);
    int c = half * 256 + threadIdx.x;
    int pa = a / 7, pb = a % 7;
    const float* base = q + (long)b * N_TOK * 512 + c;
    float s = 0.f;
#pragma unroll
    for (int i = 0; i < 8; i++) {
        int rowbase = (pa * 8 + i) * H_IMG + pb * 8;
#pragma unroll
        for (int j = 0; j < 8; j++)
            s += base[(long)(rowbase + j) * 512];
    }
    agent[((long)b * AGENT_NUM + a) * 512 + c] = s * (1.f / 64.f);
}

// ---------------------------------------------------------------------------
// Agent attention, split over n: each block handles 448 tokens (14 tiles of 32)
// and writes partial (acc, m, l). Flash-style online softmax.
// ---------------------------------------------------------------------------
__global__ __launch_bounds__(256) void agent_attn_partial(
    const unsigned short* __restrict__ kO, const unsigned short* __restrict__ vO,
    const float* __restrict__ agent,
    float* __restrict__ macc, float* __restrict__ mpart, float* __restrict__ lpart)
{
    int blk = blockIdx.x;              // (b*8+h)*7 + s
    int s = blk % N_SPLIT;
    int bh = blk / N_SPLIT;
    int b = bh >> 3, h = bh & 7;
    int tid = threadIdx.x;

    __shared__ float ah[AGENT_NUM * 64];
    __shared__ float kt[32 * 65];
    __shared__ float vt[32 * 65];
    __shared__ float sS[AGENT_NUM * 33];
    __shared__ float accL[AGENT_NUM * 65];
    __shared__ float alphaS[AGENT_NUM];

    for (int idx = tid; idx < AGENT_NUM * 64; idx += 256) {
        int a = idx >> 6, d = idx & 63;
        ah[idx] = agent[((long)b * AGENT_NUM + a) * 512 + h * 64 + d] * SCALE;
        accL[a * 65 + d] = 0.f;
    }
    float m_a = -1e30f, l_a = 0.f;
    __syncthreads();

    const unsigned short* kbase = kO + (long)b * N_TOK * 512 + h * 64;
    const unsigned short* vbase = vO + (long)b * N_TOK * 512 + h * 64;

    int nstart = s * (N_TOK / N_SPLIT);
    int nend = nstart + (N_TOK / N_SPLIT);
    for (int n0 = nstart; n0 < nend; n0 += 32) {
        for (int f = tid; f < 32 * 16; f += 256) {
            int i = f >> 4, d4 = (f & 15) << 2;
            ushort4 ku = *(const ushort4*)(kbase + (long)(n0 + i) * 512 + d4);
            ushort4 vu = *(const ushort4*)(vbase + (long)(n0 + i) * 512 + d4);
            int o = i * 65 + d4;
            kt[o + 0] = bf2f(ku.x); kt[o + 1] = bf2f(ku.y);
            kt[o + 2] = bf2f(ku.z); kt[o + 3] = bf2f(ku.w);
            vt[o + 0] = bf2f(vu.x); vt[o + 1] = bf2f(vu.y);
            vt[o + 2] = bf2f(vu.z); vt[o + 3] = bf2f(vu.w);
        }
        __syncthreads();

        for (int idx = tid; idx < AGENT_NUM * 32; idx += 256) {
            int a = idx >> 5, i = idx & 31;
            const float* ap = ah + a * 64;
            const float* kp = kt + i * 65;
            float sum = 0.f;
#pragma unroll
            for (int d = 0; d < 64; d++) sum += ap[d] * kp[d];
            sS[a * 33 + i] = sum;
        }
        __syncthreads();

        if (tid < AGENT_NUM) {
            float* sp = sS + tid * 33;
            float mx = m_a;
            for (int i = 0; i < 32; i++) mx = fmaxf(mx, sp[i]);
            float alpha = __expf(m_a - mx);
            float sum = 0.f;
            for (int i = 0; i < 32; i++) {
                float p = __expf(sp[i] - mx);
                sp[i] = p;
                sum += p;
            }
            l_a = l_a * alpha + sum;
            m_a = mx;
            alphaS[tid] = alpha;
        }
        __syncthreads();

        for (int idx = tid; idx < AGENT_NUM * 64; idx += 256) {
            int a = idx >> 6, d = idx & 63;
            const float* pp = sS + a * 33;
            float acc = accL[a * 65 + d] * alphaS[a];
#pragma unroll
            for (int i = 0; i < 32; i++) acc += pp[i] * vt[i * 65 + d];
            accL[a * 65 + d] = acc;
        }
        __syncthreads();
    }

    if (tid < AGENT_NUM) {
        mpart[(long)blk * AGENT_NUM + tid] = m_a;
        lpart[(long)blk * AGENT_NUM + tid] = l_a;
    }
    for (int idx = tid; idx < AGENT_NUM * 64; idx += 256)
        macc[(long)blk * (AGENT_NUM * 64) + idx] = accL[(idx >> 6) * 65 + (idx & 63)];
}

// Combine the N_SPLIT partials -> agent_v[b,h,a,d]
__global__ __launch_bounds__(256) void agent_attn_combine(
    const float* __restrict__ macc, const float* __restrict__ mpart,
    const float* __restrict__ lpart, float* __restrict__ agent_v)
{
    int bh = blockIdx.x;               // 0..255
    int tid = threadIdx.x;
    __shared__ float E[AGENT_NUM * N_SPLIT];
    __shared__ float Linv[AGENT_NUM];

    if (tid < AGENT_NUM) {
        float mx = -1e30f;
        for (int s = 0; s < N_SPLIT; s++)
            mx = fmaxf(mx, mpart[((long)bh * N_SPLIT + s) * AGENT_NUM + tid]);
        float l = 0.f;
        for (int s = 0; s < N_SPLIT; s++) {
            float e = __expf(mpart[((long)bh * N_SPLIT + s) * AGENT_NUM + tid] - mx);
            E[tid * N_SPLIT + s] = e;
            l += e * lpart[((long)bh * N_SPLIT + s) * AGENT_NUM + tid];
        }
        Linv[tid] = 1.f / l;
    }
    __syncthreads();

    for (int idx = tid; idx < AGENT_NUM * 64; idx += 256) {
        int a = idx >> 6;
        float acc = 0.f;
        for (int s = 0; s < N_SPLIT; s++)
            acc += E[a * N_SPLIT + s] *
                   macc[((long)bh * N_SPLIT + s) * (AGENT_NUM * 64) + idx];
        agent_v[(long)bh * (AGENT_NUM * 64) + idx] = acc * Linv[a];
    }
}

// ---------------------------------------------------------------------------
// q attention, IN-PLACE on d_out: reads q row (fp32) into regs, writes attn out
// to the same slice. Each (n, h-slice) owned by exactly one thread.
// ---------------------------------------------------------------------------
__global__ __launch_bounds__(256) void q_attn(
    float* __restrict__ q, const float* __restrict__ agent,
    const float* __restrict__ agent_v)
{
    int chunk = blockIdx.x, h = blockIdx.y, b = blockIdx.z;
    int tid = threadIdx.x;

    __shared__ float ah[AGENT_NUM * 64];
    __shared__ float av[AGENT_NUM * 64];
    for (int idx = tid; idx < AGENT_NUM * 64; idx += 256) {
        int a = idx >> 6, d = idx & 63;
        ah[idx] = agent[((long)b * AGENT_NUM + a) * 512 + h * 64 + d];
        av[idx] = agent_v[((long)b * 8 + h) * (AGENT_NUM * 64) + idx];
    }
    __syncthreads();

    int n = chunk * 256 + tid;
    if (n >= N_TOK) return;

    float* qrow = q + ((long)b * N_TOK + n) * 512 + h * 64;
    float4 q4[16];
#pragma unroll
    for (int i = 0; i < 16; i++) q4[i] = *(float4*)(qrow + i * 4);

    float sc[AGENT_NUM];
#pragma unroll
    for (int a = 0; a < AGENT_NUM; a++) {
        const float* ap = ah + a * 64;
        float s = 0.f;
#pragma unroll
        for (int i = 0; i < 16; i++) {
            s += q4[i].x * ap[i * 4 + 0] + q4[i].y * ap[i * 4 + 1]
               + q4[i].z * ap[i * 4 + 2] + q4[i].w * ap[i * 4 + 3];
        }
        sc[a] = s * SCALE;
    }
    float mx = sc[0];
#pragma unroll
    for (int a = 1; a < AGENT_NUM; a++) mx = fmaxf(mx, sc[a]);
    float sum = 0.f;
#pragma unroll
    for (int a = 0; a < AGENT_NUM; a++) { sc[a] = __expf(sc[a] - mx); sum += sc[a]; }
    float inv = 1.f / sum;

#pragma unroll
    for (int d4 = 0; d4 < 16; d4++) {
        float4 o = make_float4(0.f, 0.f, 0.f, 0.f);
#pragma unroll
        for (int a = 0; a < AGENT_NUM; a++) {
            float p = sc[a];
            const float* vp = av + a * 64 + d4 * 4;
            o.x += p * vp[0]; o.y += p * vp[1];
            o.z += p * vp[2]; o.w += p * vp[3];
        }
        o.x *= inv; o.y *= inv; o.z *= inv; o.w *= inv;
        *(float4*)(qrow + d4 * 4) = o;
    }
}

// ---------------------------------------------------------------------------
// Depthwise 3x3 conv on v (bf16, [b,n,512]) + bias, accumulated into d_out
// ---------------------------------------------------------------------------
__global__ __launch_bounds__(256) void dwc_kernel(
    const unsigned short* __restrict__ vO, const float* __restrict__ w,
    const float* __restrict__ bias, float* __restrict__ out)
{
    long flat = (long)blockIdx.x * 256 + threadIdx.x;
    int c = (int)(flat & 511);
    long bn = flat >> 9;
    int n = (int)(bn % N_TOK);
    int b = (int)(bn / N_TOK);
    int y = n / H_IMG, x = n % H_IMG;

    const unsigned short* vb = vO + (long)b * N_TOK * 512 + c;
    float acc = bias[c];
#pragma unroll
    for (int dy = 0; dy < 3; dy++) {
        int yy = y + dy - 1;
        if (yy < 0 || yy >= H_IMG) continue;
#pragma unroll
        for (int dx = 0; dx < 3; dx++) {
            int xx = x + dx - 1;
            if (xx < 0 || xx >= H_IMG) continue;
            acc += w[c * 9 + dy * 3 + dx] * bf2f(vb[(long)(yy * H_IMG + xx) * 512]);
        }
    }
    out[flat] += acc;
}

// cast d_out fp32 -> bf16 scratch (A operand of proj GEMM)
__global__ __launch_bounds__(256) void cast_copy(
    const float* __restrict__ in, unsigned short* __restrict__ out)
{
    long i = (long)blockIdx.x * 256 + threadIdx.x;   // float4 index
    float4 f = ((const float4*)in)[i];
    ushort4 u;
    u.x = f2bf(f.x); u.y = f2bf(f.y); u.z = f2bf(f.z); u.w = f2bf(f.w);
    ((ushort4*)out)[i] = u;
}

// ---------------------------------------------------------------------------
extern "C" void kernel_launch(void* const* d_in, const int* in_sizes, int n_in,
                              void* d_out, int out_size, void* d_ws, size_t ws_size,
                              hipStream_t stream)
{
    const float* x      = (const float*)d_in[0];
    const float* qkv_w  = (const float*)d_in[1];
    const float* proj_w = (const float*)d_in[2];
    const float* proj_b = (const float*)d_in[3];
    const float* dwc_w  = (const float*)d_in[4];
    const float* dwc_b  = (const float*)d_in[5];
    float* out = (float*)d_out;

    const long KV_ELEMS    = (long)M_ROWS * 512;                  // 51,380,224
    const long AGENT_ELEMS = (long)B_SZ * AGENT_NUM * 512;        // 802,816
    const long AV_ELEMS    = (long)B_SZ * 8 * AGENT_NUM * 64;     // 802,816
    const long MACC_ELEMS  = (long)B_SZ * 8 * N_SPLIT * AGENT_NUM * 64; // 5,619,712
    const long ML_ELEMS    = (long)B_SZ * 8 * N_SPLIT * AGENT_NUM;      // 87,808

    unsigned short* kbuf = (unsigned short*)d_ws;                 // also A-copy later
    unsigned short* vbuf = kbuf + KV_ELEMS;
    float* agent   = (float*)(vbuf + KV_ELEMS);
    float* agent_v = agent + AGENT_ELEMS;
    float* macc    = agent_v + AV_ELEMS;
    float* mpart   = macc + MACC_ELEMS;
    float* lpart   = mpart + ML_ELEMS;

    size_t need = (size_t)KV_ELEMS * 2 * sizeof(unsigned short)
                + (size_t)(AGENT_ELEMS + AV_ELEMS + MACC_ELEMS + 2 * ML_ELEMS) * sizeof(float);
    if (ws_size < need) return;   // output stays zero -> detectable 0.127 signature

    // 1. qkv GEMM: q -> d_out (fp32), k,v -> ws (bf16)
    sgemm_qkv<<<dim3(M_ROWS / 128, 12), 256, 0, stream>>>(x, qkv_w, out, kbuf, vbuf);

    // 2. agent = 7x7 pool of q
    pool_q<<<B_SZ * AGENT_NUM * 2, 256, 0, stream>>>(out, agent);

    // 3. agent attention (split + combine) -> agent_v
    agent_attn_partial<<<B_SZ * 8 * N_SPLIT, 256, 0, stream>>>(
        kbuf, vbuf, agent, macc, mpart, lpart);
    agent_attn_combine<<<B_SZ * 8, 256, 0, stream>>>(macc, mpart, lpart, agent_v);

    // 4. q attention, in-place on d_out
    q_attn<<<dim3((N_TOK + 255) / 256, 8, B_SZ), 256, 0, stream>>>(out, agent, agent_v);

    // 5. depthwise conv accumulate into d_out
    dwc_kernel<<<(unsigned)((long)M_ROWS * 512 / 256), 256, 0, stream>>>(
        vbuf, dwc_w, dwc_b, out);

    // 6. cast d_out -> bf16 (reuse k buffer; k is dead now)
    cast_copy<<<(unsigned)(KV_ELEMS / 4 / 256), 256, 0, stream>>>(out, kbuf);

    // 7. final projection (reads bf16 A, writes d_out)
    sgemm_proj<<<dim3(M_ROWS / 128, 4), 256, 0, stream>>>(kbuf, proj_w, proj_b, out);
}

// Round 3
// 2035.703 us; speedup vs baseline: 1.9248x; 1.9248x over previous
//
#include <hip/hip_runtime.h>

#define B_SZ 32
#define N_TOK 3136
#define C_DIM 512
#define H_IMG 56
#define NUM_HEADS 8
#define HEAD_DIM 64
#define AGENT_NUM 49
#define SCALE 0.125f
#define M_ROWS (B_SZ * N_TOK)        // 100352
#define N_SPLIT 7                    // agent-attn n-splits (448 tokens each)

typedef __bf16 bf16x8 __attribute__((ext_vector_type(8)));
typedef float f32x4 __attribute__((ext_vector_type(4)));

static __device__ __forceinline__ unsigned short f2bf(float f) {
    unsigned int u = __float_as_uint(f);
    unsigned int r = (u + 0x7fffu + ((u >> 16) & 1u)) >> 16;   // RNE
    return (unsigned short)r;
}
static __device__ __forceinline__ float bf2f(unsigned short u) {
    return __uint_as_float(((unsigned int)u) << 16);
}
// async global->LDS, 16B per lane; lds dest must be wave-uniform (HW: base + lane*16)
static __device__ __forceinline__ void load_lds16(const unsigned short* g, unsigned short* l) {
    __builtin_amdgcn_global_load_lds(
        (const __attribute__((address_space(1))) unsigned int*)g,
        (__attribute__((address_space(3))) unsigned int*)l, 16, 0, 0);
}

// generic fp32 -> bf16 cast, count must be multiple of 1024
__global__ __launch_bounds__(256) void cast_f32_bf16(
    const float* __restrict__ in, unsigned short* __restrict__ out)
{
    long i = (long)blockIdx.x * 256 + threadIdx.x;   // float4 index
    float4 f = ((const float4*)in)[i];
    ushort4 u;
    u.x = f2bf(f.x); u.y = f2bf(f.y); u.z = f2bf(f.z); u.w = f2bf(f.w);
    ((ushort4*)out)[i] = u;
}

// ---------------------------------------------------------------------------
// QKV MFMA GEMM: [M,1536] = x[M,512](fp32, cast in staging) @ qkv_wb[1536,512]^T
// 128x128 tile, BK=32, 4 waves, each wave 64x64 via 4x4 grid of 16x16x32 MFMA.
// q (cols 0:512) -> fp32 d_out;  k,v -> bf16 ws.
// ---------------------------------------------------------------------------
__global__ __launch_bounds__(256) void mfma_qkv(
    const float* __restrict__ A, const unsigned short* __restrict__ Wb,
    float* __restrict__ qO, unsigned short* __restrict__ kO,
    unsigned short* __restrict__ vO)
{
    __shared__ __align__(16) unsigned short Asm[128 * 32];
    __shared__ __align__(16) unsigned short Bsm[128 * 32];

    const int m0 = blockIdx.x * 128, n0 = blockIdx.y * 128;
    const int tid = threadIdx.x;
    const int lane = tid & 63, wave = tid >> 6;
    const int wm = wave >> 1, wn = wave & 1;

    f32x4 acc[4][4];
#pragma unroll
    for (int i = 0; i < 4; i++)
#pragma unroll
        for (int j = 0; j < 4; j++) {
            f32x4 z = {0.f, 0.f, 0.f, 0.f};
            acc[i][j] = z;
        }

    // A staging (fp32 -> bf16): thread t -> row t/2, col-half (t&1)*16
    const int arow = tid >> 1, acol = (tid & 1) * 16;
    const float* aP = A + (long)(m0 + arow) * 512 + acol;
    unsigned short* aD = Asm + arow * 32 + acol;

    // B staging via global_load_lds: round r covers LDS bytes [(r*4+wave)*1024)
    const unsigned short* bP0 = Wb + (long)(n0 + (tid >> 2)) * 512 + (tid & 3) * 8;
    const unsigned short* bP1 = bP0 + (long)64 * 512;
    unsigned short* bD0 = Bsm + (tid >> 6) * 512;          // wave-uniform
    unsigned short* bD1 = bD0 + 4 * 512;

    // fragment read addresses
    const int fr = lane & 15, fq = lane >> 4;
    const unsigned short* aF = Asm + (wm * 64 + fr) * 32 + fq * 8;
    const unsigned short* bF = Bsm + (wn * 64 + fr) * 32 + fq * 8;

    for (int k0 = 0; k0 < 512; k0 += 32) {
        load_lds16(bP0 + k0, bD0);
        load_lds16(bP1 + k0, bD1);
        float4 f0 = *(const float4*)(aP + k0 + 0);
        float4 f1 = *(const float4*)(aP + k0 + 4);
        float4 f2 = *(const float4*)(aP + k0 + 8);
        float4 f3 = *(const float4*)(aP + k0 + 12);
        ushort4 u0, u1, u2, u3;
        u0.x = f2bf(f0.x); u0.y = f2bf(f0.y); u0.z = f2bf(f0.z); u0.w = f2bf(f0.w);
        u1.x = f2bf(f1.x); u1.y = f2bf(f1.y); u1.z = f2bf(f1.z); u1.w = f2bf(f1.w);
        u2.x = f2bf(f2.x); u2.y = f2bf(f2.y); u2.z = f2bf(f2.z); u2.w = f2bf(f2.w);
        u3.x = f2bf(f3.x); u3.y = f2bf(f3.y); u3.z = f2bf(f3.z); u3.w = f2bf(f3.w);
        *(ushort4*)(aD + 0)  = u0;
        *(ushort4*)(aD + 4)  = u1;
        *(ushort4*)(aD + 8)  = u2;
        *(ushort4*)(aD + 12) = u3;
        __syncthreads();

        bf16x8 af[4], bfr[4];
#pragma unroll
        for (int i = 0; i < 4; i++) af[i]  = *(const bf16x8*)(aF + i * 16 * 32);
#pragma unroll
        for (int j = 0; j < 4; j++) bfr[j] = *(const bf16x8*)(bF + j * 16 * 32);
#pragma unroll
        for (int i = 0; i < 4; i++)
#pragma unroll
            for (int j = 0; j < 4; j++)
                acc[i][j] = __builtin_amdgcn_mfma_f32_16x16x32_bf16(
                    af[i], bfr[j], acc[i][j], 0, 0, 0);
        __syncthreads();
    }

    // epilogue: C/D layout col=lane&15, row=(lane>>4)*4+reg
    const int seg = n0 >> 9;   // 0=q,1=k,2=v (block never straddles: 128|512)
#pragma unroll
    for (int i = 0; i < 4; i++) {
        int rbase = m0 + wm * 64 + i * 16 + fq * 4;
#pragma unroll
        for (int j = 0; j < 4; j++) {
            int col  = n0 + wn * 64 + j * 16 + fr;
            int nloc = col - seg * 512;
#pragma unroll
            for (int r = 0; r < 4; r++) {
                long m = rbase + r;
                float val = acc[i][j][r];
                if (seg == 0)      qO[m * 512 + nloc] = val;
                else if (seg == 1) kO[m * 512 + nloc] = f2bf(val);
                else               vO[m * 512 + nloc] = f2bf(val);
            }
        }
    }
}

// ---------------------------------------------------------------------------
// Proj MFMA GEMM: d_out[M,512] = Ab[M,512](bf16) @ proj_wb[512,512]^T + bias
// Both operands staged via global_load_lds.
// ---------------------------------------------------------------------------
__global__ __launch_bounds__(256) void mfma_proj(
    const unsigned short* __restrict__ Ab, const unsigned short* __restrict__ Wb,
    const float* __restrict__ bias, float* __restrict__ C)
{
    __shared__ __align__(16) unsigned short Asm[128 * 32];
    __shared__ __align__(16) unsigned short Bsm[128 * 32];

    const int m0 = blockIdx.x * 128, n0 = blockIdx.y * 128;
    const int tid = threadIdx.x;
    const int lane = tid & 63, wave = tid >> 6;
    const int wm = wave >> 1, wn = wave & 1;

    f32x4 acc[4][4];
#pragma unroll
    for (int i = 0; i < 4; i++)
#pragma unroll
        for (int j = 0; j < 4; j++) {
            f32x4 z = {0.f, 0.f, 0.f, 0.f};
            acc[i][j] = z;
        }

    const unsigned short* aP0 = Ab + (long)(m0 + (tid >> 2)) * 512 + (tid & 3) * 8;
    const unsigned short* aP1 = aP0 + (long)64 * 512;
    const unsigned short* bP0 = Wb + (long)(n0 + (tid >> 2)) * 512 + (tid & 3) * 8;
    const unsigned short* bP1 = bP0 + (long)64 * 512;
    unsigned short* aD0 = Asm + (tid >> 6) * 512;   // wave-uniform
    unsigned short* aD1 = aD0 + 4 * 512;
    unsigned short* bD0 = Bsm + (tid >> 6) * 512;
    unsigned short* bD1 = bD0 + 4 * 512;

    const int fr = lane & 15, fq = lane >> 4;
    const unsigned short* aF = Asm + (wm * 64 + fr) * 32 + fq * 8;
    const unsigned short* bF = Bsm + (wn * 64 + fr) * 32 + fq * 8;

    for (int k0 = 0; k0 < 512; k0 += 32) {
        load_lds16(aP0 + k0, aD0);
        load_lds16(aP1 + k0, aD1);
        load_lds16(bP0 + k0, bD0);
        load_lds16(bP1 + k0, bD1);
        __syncthreads();

        bf16x8 af[4], bfr[4];
#pragma unroll
        for (int i = 0; i < 4; i++) af[i]  = *(const bf16x8*)(aF + i * 16 * 32);
#pragma unroll
        for (int j = 0; j < 4; j++) bfr[j] = *(const bf16x8*)(bF + j * 16 * 32);
#pragma unroll
        for (int i = 0; i < 4; i++)
#pragma unroll
            for (int j = 0; j < 4; j++)
                acc[i][j] = __builtin_amdgcn_mfma_f32_16x16x32_bf16(
                    af[i], bfr[j], acc[i][j], 0, 0, 0);
        __syncthreads();
    }

#pragma unroll
    for (int i = 0; i < 4; i++) {
        int rbase = m0 + wm * 64 + i * 16 + fq * 4;
#pragma unroll
        for (int j = 0; j < 4; j++) {
            int col = n0 + wn * 64 + j * 16 + fr;
            float bv = bias[col];
#pragma unroll
            for (int r = 0; r < 4; r++)
                C[(long)(rbase + r) * 512 + col] = acc[i][j][r] + bv;
        }
    }
}

// ---------------------------------------------------------------------------
// agent[b,a,c] = mean over 8x8 spatial block of q (q fp32, stride 512)
// ---------------------------------------------------------------------------
__global__ __launch_bounds__(256) void pool_q(
    const float* __restrict__ q, float* __restrict__ agent)
{
    int blk = blockIdx.x;
    int half = blk & 1;
    int a = (blk >> 1) % AGENT_NUM;
    int b = blk / (2 * AGENT_NUM);
    int c = half * 256 + threadIdx.x;
    int pa = a / 7, pb = a % 7;
    const float* base = q + (long)b * N_TOK * 512 + c;
    float s = 0.f;
#pragma unroll
    for (int i = 0; i < 8; i++) {
        int rowbase = (pa * 8 + i) * H_IMG + pb * 8;
#pragma unroll
        for (int j = 0; j < 8; j++)
            s += base[(long)(rowbase + j) * 512];
    }
    agent[((long)b * AGENT_NUM + a) * 512 + c] = s * (1.f / 64.f);
}

// ---------------------------------------------------------------------------
// Agent attention, split over n: each block = 448 tokens (14 tiles of 32),
// writes partial (acc, m, l). Flash-style online softmax.
// ---------------------------------------------------------------------------
__global__ __launch_bounds__(256) void agent_attn_partial(
    const unsigned short* __restrict__ kO, const unsigned short* __restrict__ vO,
    const float* __restrict__ agent,
    float* __restrict__ macc, float* __restrict__ mpart, float* __restrict__ lpart)
{
    int blk = blockIdx.x;              // (b*8+h)*7 + s
    int s = blk % N_SPLIT;
    int bh = blk / N_SPLIT;
    int b = bh >> 3, h = bh & 7;
    int tid = threadIdx.x;

    __shared__ float ah[AGENT_NUM * 64];
    __shared__ float kt[32 * 65];
    __shared__ float vt[32 * 65];
    __shared__ float sS[AGENT_NUM * 33];
    __shared__ float accL[AGENT_NUM * 65];
    __shared__ float alphaS[AGENT_NUM];

    for (int idx = tid; idx < AGENT_NUM * 64; idx += 256) {
        int a = idx >> 6, d = idx & 63;
        ah[idx] = agent[((long)b * AGENT_NUM + a) * 512 + h * 64 + d] * SCALE;
        accL[a * 65 + d] = 0.f;
    }
    float m_a = -1e30f, l_a = 0.f;
    __syncthreads();

    const unsigned short* kbase = kO + (long)b * N_TOK * 512 + h * 64;
    const unsigned short* vbase = vO + (long)b * N_TOK * 512 + h * 64;

    int nstart = s * (N_TOK / N_SPLIT);
    int nend = nstart + (N_TOK / N_SPLIT);
    for (int n0 = nstart; n0 < nend; n0 += 32) {
        for (int f = tid; f < 32 * 16; f += 256) {
            int i = f >> 4, d4 = (f & 15) << 2;
            ushort4 ku = *(const ushort4*)(kbase + (long)(n0 + i) * 512 + d4);
            ushort4 vu = *(const ushort4*)(vbase + (long)(n0 + i) * 512 + d4);
            int o = i * 65 + d4;
            kt[o + 0] = bf2f(ku.x); kt[o + 1] = bf2f(ku.y);
            kt[o + 2] = bf2f(ku.z); kt[o + 3] = bf2f(ku.w);
            vt[o + 0] = bf2f(vu.x); vt[o + 1] = bf2f(vu.y);
            vt[o + 2] = bf2f(vu.z); vt[o + 3] = bf2f(vu.w);
        }
        __syncthreads();

        for (int idx = tid; idx < AGENT_NUM * 32; idx += 256) {
            int a = idx >> 5, i = idx & 31;
            const float* ap = ah + a * 64;
            const float* kp = kt + i * 65;
            float sum = 0.f;
#pragma unroll
            for (int d = 0; d < 64; d++) sum += ap[d] * kp[d];
            sS[a * 33 + i] = sum;
        }
        __syncthreads();

        if (tid < AGENT_NUM) {
            float* sp = sS + tid * 33;
            float mx = m_a;
            for (int i = 0; i < 32; i++) mx = fmaxf(mx, sp[i]);
            float alpha = __expf(m_a - mx);
            float sum = 0.f;
            for (int i = 0; i < 32; i++) {
                float p = __expf(sp[i] - mx);
                sp[i] = p;
                sum += p;
            }
            l_a = l_a * alpha + sum;
            m_a = mx;
            alphaS[tid] = alpha;
        }
        __syncthreads();

        for (int idx = tid; idx < AGENT_NUM * 64; idx += 256) {
            int a = idx >> 6, d = idx & 63;
            const float* pp = sS + a * 33;
            float acc = accL[a * 65 + d] * alphaS[a];
#pragma unroll
            for (int i = 0; i < 32; i++) acc += pp[i] * vt[i * 65 + d];
            accL[a * 65 + d] = acc;
        }
        __syncthreads();
    }

    if (tid < AGENT_NUM) {
        mpart[(long)blk * AGENT_NUM + tid] = m_a;
        lpart[(long)blk * AGENT_NUM + tid] = l_a;
    }
    for (int idx = tid; idx < AGENT_NUM * 64; idx += 256)
        macc[(long)blk * (AGENT_NUM * 64) + idx] = accL[(idx >> 6) * 65 + (idx & 63)];
}

// Combine the N_SPLIT partials -> agent_v[b,h,a,d]
__global__ __launch_bounds__(256) void agent_attn_combine(
    const float* __restrict__ macc, const float* __restrict__ mpart,
    const float* __restrict__ lpart, float* __restrict__ agent_v)
{
    int bh = blockIdx.x;               // 0..255
    int tid = threadIdx.x;
    __shared__ float E[AGENT_NUM * N_SPLIT];
    __shared__ float Linv[AGENT_NUM];

    if (tid < AGENT_NUM) {
        float mx = -1e30f;
        for (int s = 0; s < N_SPLIT; s++)
            mx = fmaxf(mx, mpart[((long)bh * N_SPLIT + s) * AGENT_NUM + tid]);
        float l = 0.f;
        for (int s = 0; s < N_SPLIT; s++) {
            float e = __expf(mpart[((long)bh * N_SPLIT + s) * AGENT_NUM + tid] - mx);
            E[tid * N_SPLIT + s] = e;
            l += e * lpart[((long)bh * N_SPLIT + s) * AGENT_NUM + tid];
        }
        Linv[tid] = 1.f / l;
    }
    __syncthreads();

    for (int idx = tid; idx < AGENT_NUM * 64; idx += 256) {
        int a = idx >> 6;
        float acc = 0.f;
        for (int s = 0; s < N_SPLIT; s++)
            acc += E[a * N_SPLIT + s] *
                   macc[((long)bh * N_SPLIT + s) * (AGENT_NUM * 64) + idx];
        agent_v[(long)bh * (AGENT_NUM * 64) + idx] = acc * Linv[a];
    }
}

// ---------------------------------------------------------------------------
// q attention, IN-PLACE on d_out (q fp32): each (n, h-slice) owned by 1 thread
// ---------------------------------------------------------------------------
__global__ __launch_bounds__(256) void q_attn(
    float* __restrict__ q, const float* __restrict__ agent,
    const float* __restrict__ agent_v)
{
    int chunk = blockIdx.x, h = blockIdx.y, b = blockIdx.z;
    int tid = threadIdx.x;

    __shared__ float ah[AGENT_NUM * 64];
    __shared__ float av[AGENT_NUM * 64];
    for (int idx = tid; idx < AGENT_NUM * 64; idx += 256) {
        int a = idx >> 6, d = idx & 63;
        ah[idx] = agent[((long)b * AGENT_NUM + a) * 512 + h * 64 + d];
        av[idx] = agent_v[((long)b * 8 + h) * (AGENT_NUM * 64) + idx];
    }
    __syncthreads();

    int n = chunk * 256 + tid;
    if (n >= N_TOK) return;

    float* qrow = q + ((long)b * N_TOK + n) * 512 + h * 64;
    float4 q4[16];
#pragma unroll
    for (int i = 0; i < 16; i++) q4[i] = *(float4*)(qrow + i * 4);

    float sc[AGENT_NUM];
#pragma unroll
    for (int a = 0; a < AGENT_NUM; a++) {
        const float* ap = ah + a * 64;
        float s = 0.f;
#pragma unroll
        for (int i = 0; i < 16; i++) {
            s += q4[i].x * ap[i * 4 + 0] + q4[i].y * ap[i * 4 + 1]
               + q4[i].z * ap[i * 4 + 2] + q4[i].w * ap[i * 4 + 3];
        }
        sc[a] = s * SCALE;
    }
    float mx = sc[0];
#pragma unroll
    for (int a = 1; a < AGENT_NUM; a++) mx = fmaxf(mx, sc[a]);
    float sum = 0.f;
#pragma unroll
    for (int a = 0; a < AGENT_NUM; a++) { sc[a] = __expf(sc[a] - mx); sum += sc[a]; }
    float inv = 1.f / sum;

#pragma unroll
    for (int d4 = 0; d4 < 16; d4++) {
        float4 o = make_float4(0.f, 0.f, 0.f, 0.f);
#pragma unroll
        for (int a = 0; a < AGENT_NUM; a++) {
            float p = sc[a];
            const float* vp = av + a * 64 + d4 * 4;
            o.x += p * vp[0]; o.y += p * vp[1];
            o.z += p * vp[2]; o.w += p * vp[3];
        }
        o.x *= inv; o.y *= inv; o.z *= inv; o.w *= inv;
        *(float4*)(qrow + d4 * 4) = o;
    }
}

// ---------------------------------------------------------------------------
// Depthwise 3x3 conv on v (bf16) + bias, accumulated into d_out
// ---------------------------------------------------------------------------
__global__ __launch_bounds__(256) void dwc_kernel(
    const unsigned short* __restrict__ vO, const float* __restrict__ w,
    const float* __restrict__ bias, float* __restrict__ out)
{
    long flat = (long)blockIdx.x * 256 + threadIdx.x;
    int c = (int)(flat & 511);
    long bn = flat >> 9;
    int n = (int)(bn % N_TOK);
    int b = (int)(bn / N_TOK);
    int y = n / H_IMG, x = n % H_IMG;

    const unsigned short* vb = vO + (long)b * N_TOK * 512 + c;
    float acc = bias[c];
#pragma unroll
    for (int dy = 0; dy < 3; dy++) {
        int yy = y + dy - 1;
        if (yy < 0 || yy >= H_IMG) continue;
#pragma unroll
        for (int dx = 0; dx < 3; dx++) {
            int xx = x + dx - 1;
            if (xx < 0 || xx >= H_IMG) continue;
            acc += w[c * 9 + dy * 3 + dx] * bf2f(vb[(long)(yy * H_IMG + xx) * 512]);
        }
    }
    out[flat] += acc;
}

// ---------------------------------------------------------------------------
extern "C" void kernel_launch(void* const* d_in, const int* in_sizes, int n_in,
                              void* d_out, int out_size, void* d_ws, size_t ws_size,
                              hipStream_t stream)
{
    const float* x      = (const float*)d_in[0];
    const float* qkv_w  = (const float*)d_in[1];
    const float* proj_w = (const float*)d_in[2];
    const float* proj_b = (const float*)d_in[3];
    const float* dwc_w  = (const float*)d_in[4];
    const float* dwc_b  = (const float*)d_in[5];
    float* out = (float*)d_out;

    const long KV_ELEMS    = (long)M_ROWS * 512;                  // 51,380,224
    const long QKVW_ELEMS  = 1536L * 512;                         // 786,432
    const long PROJW_ELEMS = 512L * 512;                          // 262,144
    const long AGENT_ELEMS = (long)B_SZ * AGENT_NUM * 512;
    const long AV_ELEMS    = (long)B_SZ * 8 * AGENT_NUM * 64;
    const long MACC_ELEMS  = (long)B_SZ * 8 * N_SPLIT * AGENT_NUM * 64;
    const long ML_ELEMS    = (long)B_SZ * 8 * N_SPLIT * AGENT_NUM;

    unsigned short* kbuf    = (unsigned short*)d_ws;   // reused as proj-A later
    unsigned short* vbuf    = kbuf + KV_ELEMS;
    unsigned short* qkv_wb  = vbuf + KV_ELEMS;
    unsigned short* proj_wb = qkv_wb + QKVW_ELEMS;
    float* agent   = (float*)(proj_wb + PROJW_ELEMS);
    float* agent_v = agent + AGENT_ELEMS;
    float* macc    = agent_v + AV_ELEMS;
    float* mpart   = macc + MACC_ELEMS;
    float* lpart   = mpart + ML_ELEMS;

    size_t need = (size_t)(2 * KV_ELEMS + QKVW_ELEMS + PROJW_ELEMS) * 2
                + (size_t)(AGENT_ELEMS + AV_ELEMS + MACC_ELEMS + 2 * ML_ELEMS) * 4;
    if (ws_size < need) return;

    // 0. cast weights to bf16
    cast_f32_bf16<<<(unsigned)(QKVW_ELEMS / 1024), 256, 0, stream>>>(qkv_w, qkv_wb);
    cast_f32_bf16<<<(unsigned)(PROJW_ELEMS / 1024), 256, 0, stream>>>(proj_w, proj_wb);

    // 1. qkv MFMA GEMM: q -> d_out (fp32), k,v -> ws (bf16)
    mfma_qkv<<<dim3(M_ROWS / 128, 12), 256, 0, stream>>>(x, qkv_wb, out, kbuf, vbuf);

    // 2. agent = 7x7 pool of q
    pool_q<<<B_SZ * AGENT_NUM * 2, 256, 0, stream>>>(out, agent);

    // 3. agent attention (split + combine) -> agent_v
    agent_attn_partial<<<B_SZ * 8 * N_SPLIT, 256, 0, stream>>>(
        kbuf, vbuf, agent, macc, mpart, lpart);
    agent_attn_combine<<<B_SZ * 8, 256, 0, stream>>>(macc, mpart, lpart, agent_v);

    // 4. q attention, in-place on d_out
    q_attn<<<dim3((N_TOK + 255) / 256, 8, B_SZ), 256, 0, stream>>>(out, agent, agent_v);

    // 5. depthwise conv accumulate into d_out
    dwc_kernel<<<(unsigned)((long)M_ROWS * 512 / 256), 256, 0, stream>>>(
        vbuf, dwc_w, dwc_b, out);

    // 6. cast d_out -> bf16 (k buffer is dead now)
    cast_f32_bf16<<<(unsigned)(KV_ELEMS / 1024), 256, 0, stream>>>(out, kbuf);

    // 7. final projection (bf16 MFMA, fp32 epilogue + bias)
    mfma_proj<<<dim3(M_ROWS / 128, 4), 256, 0, stream>>>(kbuf, proj_wb, proj_b, out);
}